// Round 1
// baseline (2281.516 us; speedup 1.0000x reference)
//
#include <hip/hip_runtime.h>

#define B_  128
#define T_  256
#define D_  256
#define U_  256
#define TU  768      // 3*U
#define TC  64       // timestep chunk
#define NC  (T_/TC)  // 4 chunks

// ---------------- B-spline (order 3, grid h=0.4, points g[i] = -1 + 0.4*(i-3), i=0..11) ----------
__device__ __forceinline__ float bspline_dot(float x, const float* sw) {
    float b[11];
#pragma unroll
    for (int i = 0; i < 11; ++i) {
        float g0 = -1.f + 0.4f * (float)(i - 3);
        float g1 = -1.f + 0.4f * (float)(i - 2);
        b[i] = (x >= g0 && x < g1) ? 1.f : 0.f;
    }
#pragma unroll
    for (int k = 1; k <= 3; ++k) {
        float inv = 1.f / (0.4f * (float)k);
#pragma unroll
        for (int i = 0; i + k < 11; ++i) {
            float gi   = -1.f + 0.4f * (float)(i - 3);
            float gik1 = gi + 0.4f * (float)(k + 1);
            b[i] = (x - gi) * inv * b[i] + (gik1 - x) * inv * b[i + 1];
        }
    }
    float r = 0.f;
#pragma unroll
    for (int c = 0; c < 8; ++c) r += b[c] * sw[c];
    return r;
}

__device__ __forceinline__ float sigm(float x) { return 1.f / (1.f + expf(-x)); }

// ---------------- K0: zero the recurrent state ----------------
__global__ void k0_init(float* __restrict__ wh, float* __restrict__ wc, float* __restrict__ wsub) {
    int i = blockIdx.x * 256 + threadIdx.x;          // grid 128 -> 32768
    wh[i] = 0.f;
    wc[i] = 0.f;
    if (i < 3 * B_) wsub[i] = 0.f;
}

// ---------------- K1: A[b][tl][j] = x[b, t0+tl, :] @ kernel + bias  (M=8192, N=768, K=256) -------
__global__ __launch_bounds__(256) void k1_gemm(const float* __restrict__ X,
                                               const float* __restrict__ Km,
                                               const float* __restrict__ bias,
                                               float* __restrict__ A, int t0) {
    __shared__ float Xs[16][68];   // [k][m], row stride 272B (16B-aligned)
    __shared__ float Ks[16][68];   // [k][n]
    const int bm  = blockIdx.x * 64;
    const int bn  = blockIdx.y * 64;
    const int tid = threadIdx.x;
    const int ty = tid >> 4, tx = tid & 15;

    // A-tile load mapping: 4 threads per row
    const int lr  = tid >> 2;            // 0..63
    const int lk4 = (tid & 3) * 4;       // 0,4,8,12
    const int r   = bm + lr;             // global row in chunk
    const int b   = r >> 6;              // TC=64
    const int tl  = r & 63;
    const float* xrow = X + (size_t)(b * T_ + t0 + tl) * D_;

    // K-tile load mapping
    const int kr  = tid >> 4;            // 0..15
    const int kn4 = (tid & 15) * 4;      // 0..60

    float acc[4][4] = {};
    for (int kb = 0; kb < 256; kb += 16) {
        float4 xv = *(const float4*)(xrow + kb + lk4);
        Xs[lk4 + 0][lr] = xv.x;
        Xs[lk4 + 1][lr] = xv.y;
        Xs[lk4 + 2][lr] = xv.z;
        Xs[lk4 + 3][lr] = xv.w;
        *(float4*)&Ks[kr][kn4] = *(const float4*)(Km + (size_t)(kb + kr) * TU + bn + kn4);
        __syncthreads();
#pragma unroll
        for (int k = 0; k < 16; ++k) {
            float4 av = *(float4*)&Xs[k][ty * 4];
            float4 bv = *(float4*)&Ks[k][tx * 4];
            acc[0][0] += av.x * bv.x; acc[0][1] += av.x * bv.y; acc[0][2] += av.x * bv.z; acc[0][3] += av.x * bv.w;
            acc[1][0] += av.y * bv.x; acc[1][1] += av.y * bv.y; acc[1][2] += av.y * bv.z; acc[1][3] += av.y * bv.w;
            acc[2][0] += av.z * bv.x; acc[2][1] += av.z * bv.y; acc[2][2] += av.z * bv.z; acc[2][3] += av.z * bv.w;
            acc[3][0] += av.w * bv.x; acc[3][1] += av.w * bv.y; acc[3][2] += av.w * bv.z; acc[3][3] += av.w * bv.w;
        }
        __syncthreads();
    }
    float4 bv = *(const float4*)(bias + bn + tx * 4);
#pragma unroll
    for (int i = 0; i < 4; ++i) {
        float4 o;
        o.x = acc[i][0] + bv.x; o.y = acc[i][1] + bv.y;
        o.z = acc[i][2] + bv.z; o.w = acc[i][3] + bv.w;
        *(float4*)(A + (size_t)(bm + ty * 4 + i) * TU + bn + tx * 4) = o;
    }
}

// ---------------- K2: persistent recurrence over one T-chunk, one WG per batch element -----------
__global__ __launch_bounds__(768) void k2_rec(const float* __restrict__ A,     // [B][TC][768]
                                              const float* __restrict__ X,     // [B][T][256]
                                              const float* __restrict__ R,     // [256][768]
                                              const float* __restrict__ stk,   // [3][2]
                                              const float* __restrict__ strk,  // [3][512]
                                              const float* __restrict__ aggw,  // [3][256]
                                              const float* __restrict__ aggb,  // [256]
                                              const float* __restrict__ kbw,   // [3][256]
                                              const float* __restrict__ ksw,   // [3][256][8]
                                              float* __restrict__ out,         // [B][T][256]
                                              float* __restrict__ ws_h,
                                              float* __restrict__ ws_c,
                                              float* __restrict__ ws_sub,
                                              int t0) {
    __shared__ float hs[256];
    __shared__ float xs[256];
    __shared__ float zs[768];
    __shared__ float subs[3];
    __shared__ float so[3];
    __shared__ float red[12];

    const int b   = blockIdx.x;
    const int tid = threadIdx.x;
    const int s   = tid >> 8;        // 0..2
    const int d   = tid & 255;       // 0..255

    // per-thread stationary weights
    const float skx_r = strk[s * 512 + d];
    const float skh_r = strk[s * 512 + 256 + d];
    const float bw_r  = kbw[s * 256 + d];
    float sw_r[8];
#pragma unroll
    for (int c = 0; c < 8; ++c) sw_r[c] = ksw[(size_t)(s * 256 + d) * 8 + c];

    float srk_h3 = 0.f, srk_x3 = 0.f;
    if (tid < 3) { srk_h3 = stk[tid * 2 + 0]; srk_x3 = stk[tid * 2 + 1]; }

    float aw0 = 0.f, aw1 = 0.f, aw2 = 0.f, ab_r = 0.f, c_reg = 0.f;
    if (tid < 256) {
        aw0 = aggw[tid]; aw1 = aggw[256 + tid]; aw2 = aggw[512 + tid];
        ab_r = aggb[tid];
        c_reg   = ws_c[b * 256 + tid];
        hs[tid] = ws_h[b * 256 + tid];
    }
    if (tid < 3) subs[tid] = ws_sub[b * 3 + tid];
    __syncthreads();

    const float* Rp = R + tid;

    for (int tl = 0; tl < TC; ++tl) {
        const int t = t0 + tl;
        const float az = A[((size_t)b * TC + tl) * TU + tid];
        if (tid < 256) xs[tid] = X[((size_t)b * T_ + t) * D_ + tid];
        __syncthreads();

        // z[j=tid] = az + sum_u h[u] * R[u][j]
        float acc = az;
#pragma unroll 4
        for (int uu = 0; uu < 256; uu += 4) {
            float4 h4 = *(const float4*)&hs[uu];
            acc += h4.x * Rp[(uu + 0) * TU];
            acc += h4.y * Rp[(uu + 1) * TU];
            acc += h4.z * Rp[(uu + 2) * TU];
            acc += h4.w * Rp[(uu + 3) * TU];
        }
        zs[tid] = acc;

        // KAN: one (s,d) pair per thread
        const float sub_old = subs[s];
        const float a_in = xs[d] * skx_r + sub_old * skh_r;
        float val = a_in * sigm(a_in) * bw_r + bspline_dot(a_in, sw_r);
        // wave reduce (64-wide)
#pragma unroll
        for (int off = 32; off > 0; off >>= 1) val += __shfl_down(val, off);
        if ((tid & 63) == 0) red[tid >> 6] = val;
        __syncthreads();

        if (tid < 3) {
            float so_ = red[tid * 4] + red[tid * 4 + 1] + red[tid * 4 + 2] + red[tid * 4 + 3];
            so[tid] = so_;
            float old = subs[tid];
            subs[tid] = srk_h3 * so_ + srk_x3 * old;
        }
        __syncthreads();

        if (tid < 256) {
            const float zi = zs[tid], zf = zs[256 + tid], zc = zs[512 + tid];
            const float ig = sigm(zi);
            const float fg = sigm(zf);
            c_reg = fg * c_reg + ig * tanhf(zc);
            const float og = sigm(so[0] * aw0 + so[1] * aw1 + so[2] * aw2 + ab_r);
            const float hn = og * tanhf(c_reg);
            hs[tid] = hn;
            out[((size_t)b * T_ + t) * U_ + tid] = hn;
        }
        __syncthreads();
    }

    // save state for next chunk
    if (tid < 256) {
        ws_h[b * 256 + tid] = hs[tid];
        ws_c[b * 256 + tid] = c_reg;
    }
    if (tid < 3) ws_sub[b * 3 + tid] = subs[tid];
}

extern "C" void kernel_launch(void* const* d_in, const int* in_sizes, int n_in,
                              void* d_out, int out_size, void* d_ws, size_t ws_size,
                              hipStream_t stream) {
    const float* x    = (const float*)d_in[0];
    const float* Kmat = (const float*)d_in[1];
    const float* R    = (const float*)d_in[2];
    const float* bias = (const float*)d_in[3];
    const float* stk  = (const float*)d_in[4];
    const float* strk = (const float*)d_in[5];
    const float* aggw = (const float*)d_in[6];
    const float* aggb = (const float*)d_in[7];
    const float* kbw  = (const float*)d_in[8];
    const float* ksw  = (const float*)d_in[9];
    float* out = (float*)d_out;

    float* ws   = (float*)d_ws;
    float* A    = ws;                             // B_*TC*TU = 6,291,456 floats (24 MB)
    float* wh   = A + (size_t)B_ * TC * TU;       // 32768
    float* wc   = wh + B_ * U_;                   // 32768
    float* wsub = wc + B_ * U_;                   // 384

    k0_init<<<dim3(B_), dim3(256), 0, stream>>>(wh, wc, wsub);
    for (int ci = 0; ci < NC; ++ci) {
        k1_gemm<<<dim3((B_ * TC) / 64, TU / 64), dim3(256), 0, stream>>>(x, Kmat, bias, A, ci * TC);
        k2_rec<<<dim3(B_), dim3(768), 0, stream>>>(A, x, R, stk, strk, aggw, aggb, kbw, ksw,
                                                   out, wh, wc, wsub, ci * TC);
    }
}

// Round 2
// 2228.215 us; speedup vs baseline: 1.0239x; 1.0239x over previous
//
#include <hip/hip_runtime.h>

#define B_  128
#define T_  256
#define D_  256
#define U_  256
#define TU  768      // 3*U
#define TC  64       // timestep chunk
#define NC  (T_/TC)  // 4 chunks

__device__ __forceinline__ float sigm(float x) { return 1.f / (1.f + __expf(-x)); }

__device__ __forceinline__ float rdlane(float v, int l) {
    return __int_as_float(__builtin_amdgcn_readlane(__float_as_int(v), l));
}

// direct cubic B-spline eval: grid cells [g_j, g_j+0.4), g_j = -2.2 + 0.4*j, j=0..10
// nonzero basis m = j-3..j (clipped to 0..7); coeffs at ksw_lds[u*9 + m]
__device__ __forceinline__ float spline_eval(float x, const float* __restrict__ ksw_lds, int u) {
    float xc = (x + 2.2f) * 2.5f;
    float fj = floorf(xc);
    int   j  = (int)fj;
    float tl = xc - fj;
    float t2 = tl * tl, t3 = t2 * tl;
    float om = 1.f - tl;
    const float S = 1.f / 6.f;
    float w0 = om * om * om * S;                          // m = j-3
    float w1 = (3.f * t3 - 6.f * t2 + 4.f) * S;           // m = j-2
    float w2 = (-3.f * t3 + 3.f * t2 + 3.f * tl + 1.f) * S; // m = j-1
    float w3 = t3 * S;                                    // m = j
    bool  v  = (j >= 0) && (j <= 10);
    float r  = 0.f;
#pragma unroll
    for (int k = 0; k < 4; ++k) {
        int   m  = j - 3 + k;
        bool  ok = v && (m >= 0) && (m <= 7);
        int   mc = min(max(m, 0), 7);
        float wk = (k == 0) ? w0 : (k == 1) ? w1 : (k == 2) ? w2 : w3;
        float cf = ksw_lds[u * 9 + mc];
        r += ok ? wk * cf : 0.f;
    }
    return r;
}

// ---------------- K0: zero recurrent state + init exchange flags ----------------
__global__ void k0_init(float* __restrict__ wh, float* __restrict__ wc,
                        float* __restrict__ wsub, int* __restrict__ flags) {
    int i = blockIdx.x * 256 + threadIdx.x;          // grid 128 -> 32768
    wh[i] = 0.f;
    wc[i] = 0.f;
    if (i < 3 * B_) wsub[i] = 0.f;
    if (i < 2 * B_) flags[i] = -1;
}

// ---------------- K1: A[b][tl][j] = x[b, t0+tl, :] @ kernel + bias ----------------
__global__ __launch_bounds__(256) void k1_gemm(const float* __restrict__ X,
                                               const float* __restrict__ Km,
                                               const float* __restrict__ bias,
                                               float* __restrict__ A, int t0) {
    __shared__ float Xs[16][68];
    __shared__ float Ks[16][68];
    const int bm  = blockIdx.x * 64;
    const int bn  = blockIdx.y * 64;
    const int tid = threadIdx.x;
    const int ty = tid >> 4, tx = tid & 15;

    const int lr  = tid >> 2;
    const int lk4 = (tid & 3) * 4;
    const int rr  = bm + lr;
    const int b   = rr >> 6;
    const int tl  = rr & 63;
    const float* xrow = X + (size_t)(b * T_ + t0 + tl) * D_;

    const int kr  = tid >> 4;
    const int kn4 = (tid & 15) * 4;

    float acc[4][4] = {};
    for (int kb = 0; kb < 256; kb += 16) {
        float4 xv = *(const float4*)(xrow + kb + lk4);
        Xs[lk4 + 0][lr] = xv.x;
        Xs[lk4 + 1][lr] = xv.y;
        Xs[lk4 + 2][lr] = xv.z;
        Xs[lk4 + 3][lr] = xv.w;
        *(float4*)&Ks[kr][kn4] = *(const float4*)(Km + (size_t)(kb + kr) * TU + bn + kn4);
        __syncthreads();
#pragma unroll
        for (int k = 0; k < 16; ++k) {
            float4 av = *(float4*)&Xs[k][ty * 4];
            float4 bv = *(float4*)&Ks[k][tx * 4];
            acc[0][0] += av.x * bv.x; acc[0][1] += av.x * bv.y; acc[0][2] += av.x * bv.z; acc[0][3] += av.x * bv.w;
            acc[1][0] += av.y * bv.x; acc[1][1] += av.y * bv.y; acc[1][2] += av.y * bv.z; acc[1][3] += av.y * bv.w;
            acc[2][0] += av.z * bv.x; acc[2][1] += av.z * bv.y; acc[2][2] += av.z * bv.z; acc[2][3] += av.z * bv.w;
            acc[3][0] += av.w * bv.x; acc[3][1] += av.w * bv.y; acc[3][2] += av.w * bv.z; acc[3][3] += av.w * bv.w;
        }
        __syncthreads();
    }
    float4 bv = *(const float4*)(bias + bn + tx * 4);
#pragma unroll
    for (int i = 0; i < 4; ++i) {
        float4 o;
        o.x = acc[i][0] + bv.x; o.y = acc[i][1] + bv.y;
        o.z = acc[i][2] + bv.z; o.w = acc[i][3] + bv.w;
        *(float4*)(A + (size_t)(bm + ty * 4 + i) * TU + bn + tx * 4) = o;
    }
}

// ---------------- K2: pair-split recurrence, R stationary in VGPRs ----------------
// 256 blocks: block (b = idx&127, r = idx>>7) owns output units ui = r*128 .. r*128+127.
// Thread (w = tid>>6, lane): p = w&3 -> u-range p*64..p*64+63; c = (w>>2)*64 + lane.
// Rf[g][uu] = R[p*64+uu][g*256 + r*128 + c], 192 VGPRs stationary.
__global__ __launch_bounds__(512, 2) void k2_rec(const float* __restrict__ A,
                                                 const float* __restrict__ X,
                                                 const float* __restrict__ R,
                                                 const float* __restrict__ stk,
                                                 const float* __restrict__ strk,
                                                 const float* __restrict__ aggw,
                                                 const float* __restrict__ aggb,
                                                 const float* __restrict__ kbw,
                                                 const float* __restrict__ ksw,
                                                 float* __restrict__ out,
                                                 float* __restrict__ ws_h,
                                                 float* __restrict__ ws_c,
                                                 float* __restrict__ ws_sub,
                                                 float* __restrict__ xh,    // [B][2][256]
                                                 int* __restrict__ flags,   // [B][2]
                                                 int t0) {
    __shared__ float hs[256];
    __shared__ float xs[256];
    __shared__ float zred[8][64][3];
    __shared__ float kred[768];
    __shared__ float so_l[3];
    __shared__ float subs[3];
    __shared__ float st2[6];
    __shared__ float ksw_lds[768 * 9];

    const int tid  = threadIdx.x;
    const int lane = tid & 63;
    const int w    = tid >> 6;
    const int p    = w & 3;
    const int c    = ((w >> 2) << 6) | lane;   // 0..127
    const int b    = blockIdx.x & 127;
    const int r    = blockIdx.x >> 7;
    const int ui   = r * 128 + c;              // global output-unit index
    const bool pstate = (p == 0);              // waves 0 and 4 hold gate state

    // ---- stationary R fragment: 192 VGPRs ----
    float Rf[3][64];
#pragma unroll
    for (int g = 0; g < 3; ++g)
#pragma unroll
        for (int uu = 0; uu < 64; ++uu)
            Rf[g][uu] = R[(size_t)(p * 64 + uu) * TU + g * 256 + ui];

    // ---- KAN stationary weights (unit u0 = tid; u1 = tid+512 for tid<256) ----
    const int s0 = tid >> 8, d0 = tid & 255;
    const float skx0 = strk[s0 * 512 + d0];
    const float skh0 = strk[s0 * 512 + 256 + d0];
    const float bw0  = kbw[tid];
    float skx1 = 0.f, skh1 = 0.f, bw1 = 0.f;
    if (tid < 256) {
        skx1 = strk[2 * 512 + tid];
        skh1 = strk[2 * 512 + 256 + tid];
        bw1  = kbw[512 + tid];
    }

    const float aw0 = aggw[ui], aw1 = aggw[256 + ui], aw2 = aggw[512 + ui], ab = aggb[ui];
    float c_reg = ws_c[b * 256 + ui];

    for (int i = tid; i < 768 * 8; i += 512) ksw_lds[(i >> 3) * 9 + (i & 7)] = ksw[i];
    if (tid < 256) hs[tid] = ws_h[b * 256 + tid];
    if (tid < 3)   subs[tid] = ws_sub[b * 3 + tid];
    if (tid < 6)   st2[tid] = stk[tid];

    int* pflag = &flags[b * 2 + (1 - r)];

    for (int tl = 0; tl < TC; ++tl) {
        const int t = t0 + tl;

        // ---- phase1: stage x_t, prefetch A ----
        float az0 = 0.f, az1 = 0.f, az2 = 0.f;
        if (pstate) {
            const float* Ap = A + ((size_t)b * TC + tl) * TU + ui;
            az0 = Ap[0]; az1 = Ap[256]; az2 = Ap[512];
        }
        if (tid < 256) xs[tid] = X[((size_t)b * T_ + t) * D_ + tid];
        __syncthreads();   // sync1: xs (and init LDS on first iter) visible

        // ---- phase2: KAN evals (no h dependency) + fetch partner h-half ----
        {
            float a0 = xs[d0] * skx0 + subs[s0] * skh0;
            kred[tid] = a0 * sigm(a0) * bw0 + spline_eval(a0, ksw_lds, tid);
        }
        if (tid < 256) {
            float a1 = xs[tid] * skx1 + subs[2] * skh1;
            kred[512 + tid] = a1 * sigm(a1) * bw1 + spline_eval(a1, ksw_lds, 512 + tid);
        }
        if (tl > 0 && tid < 128) {
            const int uidx = (1 - r) * 128 + tid;
            while (__hip_atomic_load(pflag, __ATOMIC_ACQUIRE, __HIP_MEMORY_SCOPE_AGENT) < t - 1) {}
            hs[uidx] = __hip_atomic_load(&xh[((size_t)b * 2 + ((t - 1) & 1)) * 256 + uidx],
                                         __ATOMIC_RELAXED, __HIP_MEMORY_SCOPE_AGENT);
        }
        __syncthreads();   // sync2: kred + full hs ready

        // ---- phase3: GEMV partials, R stationary ----
        {
            float hreg = hs[p * 64 + lane];
            float a0 = 0.f, a1 = 0.f, a2 = 0.f;
#pragma unroll
            for (int uu = 0; uu < 64; ++uu) {
                float hu = rdlane(hreg, uu);
                a0 = fmaf(hu, Rf[0][uu], a0);
                a1 = fmaf(hu, Rf[1][uu], a1);
                a2 = fmaf(hu, Rf[2][uu], a2);
            }
            zred[w][lane][0] = a0;
            zred[w][lane][1] = a1;
            zred[w][lane][2] = a2;
        }
        __syncthreads();   // sync3

        // ---- phase4: KAN reduce (one wave per s) ----
        if (w < 3) {
            float v = kred[w * 256 + lane] + kred[w * 256 + 64 + lane]
                    + kred[w * 256 + 128 + lane] + kred[w * 256 + 192 + lane];
#pragma unroll
            for (int m = 32; m > 0; m >>= 1) v += __shfl_xor(v, m, 64);
            if (lane == 0) {
                so_l[w] = v;
                subs[w] = st2[w * 2] * v + st2[w * 2 + 1] * subs[w];
            }
        }
        __syncthreads();   // sync4

        // ---- phase5: gates + state update + publish ----
        if (pstate) {
            float z0 = az0, z1 = az1, z2 = az2;
#pragma unroll
            for (int q = 0; q < 4; ++q) {
                z0 += zred[w + q][lane][0];
                z1 += zred[w + q][lane][1];
                z2 += zred[w + q][lane][2];
            }
            float ig = sigm(z0);
            float fg = sigm(z1);
            c_reg = fg * c_reg + ig * tanhf(z2);
            float og = sigm(so_l[0] * aw0 + so_l[1] * aw1 + so_l[2] * aw2 + ab);
            float hn = og * tanhf(c_reg);
            hs[ui] = hn;
            out[((size_t)b * T_ + t) * U_ + ui] = hn;
            if (tl < TC - 1) {
                __hip_atomic_store(&xh[((size_t)b * 2 + (t & 1)) * 256 + ui], hn,
                                   __ATOMIC_RELAXED, __HIP_MEMORY_SCOPE_AGENT);
            } else {
                ws_h[b * 256 + ui] = hn;
                ws_c[b * 256 + ui] = c_reg;
            }
        }
        __syncthreads();   // sync5: publishes drained (barrier waits vmcnt)
        if (tid == 0 && tl < TC - 1)
            __hip_atomic_store(&flags[b * 2 + r], t, __ATOMIC_RELEASE, __HIP_MEMORY_SCOPE_AGENT);
    }

    if (tid < 3) ws_sub[b * 3 + tid] = subs[tid];
}

extern "C" void kernel_launch(void* const* d_in, const int* in_sizes, int n_in,
                              void* d_out, int out_size, void* d_ws, size_t ws_size,
                              hipStream_t stream) {
    const float* x    = (const float*)d_in[0];
    const float* Kmat = (const float*)d_in[1];
    const float* R    = (const float*)d_in[2];
    const float* bias = (const float*)d_in[3];
    const float* stk  = (const float*)d_in[4];
    const float* strk = (const float*)d_in[5];
    const float* aggw = (const float*)d_in[6];
    const float* aggb = (const float*)d_in[7];
    const float* kbw  = (const float*)d_in[8];
    const float* ksw  = (const float*)d_in[9];
    float* out = (float*)d_out;

    float* ws   = (float*)d_ws;
    float* A    = ws;                             // 6,291,456 floats (24 MB)
    float* wh   = A + (size_t)B_ * TC * TU;       // 32768
    float* wc   = wh + B_ * U_;                   // 32768
    float* wsub = wc + B_ * U_;                   // 384 (pad to 512)
    float* xh   = wsub + 512;                     // B*2*256 = 65536
    int*   flg  = (int*)(xh + (size_t)B_ * 2 * 256);  // 256 ints

    k0_init<<<dim3(B_), dim3(256), 0, stream>>>(wh, wc, wsub, flg);
    for (int ci = 0; ci < NC; ++ci) {
        k1_gemm<<<dim3((B_ * TC) / 64, TU / 64), dim3(256), 0, stream>>>(x, Kmat, bias, A, ci * TC);
        k2_rec<<<dim3(2 * B_), dim3(512), 0, stream>>>(A, x, R, stk, strk, aggw, aggb, kbw, ksw,
                                                       out, wh, wc, wsub, xh, flg, ci * TC);
    }
}